// Round 6
// baseline (204.268 us; speedup 1.0000x reference)
//
#include <hip/hip_runtime.h>
#include <hip/hip_bf16.h>

typedef __bf16 bf16x8 __attribute__((ext_vector_type(8)));
typedef float f32x4 __attribute__((ext_vector_type(4)));
typedef float f32x16 __attribute__((ext_vector_type(16)));

// row-pair XOR swizzle: logical (row n of 64B, 16B-chunk k) -> byte offset
__device__ __forceinline__ int swz(int n, int k) {
  int pair = n >> 1;
  int s = (((n & 1) << 2) | k) ^ (pair & 7);
  return (pair << 7) + (s << 4);
}

__device__ __forceinline__ void load_lds16(const void* g, void* l) {
  __builtin_amdgcn_global_load_lds((const __attribute__((address_space(1))) void*)g,
                                   (__attribute__((address_space(3))) void*)l, 16, 0, 0);
}

// ---------- prep_x: f32 NCHW -> bf16 padded [b][grp4][98][98][32ic], border-zero fused ----------
__global__ __launch_bounds__(512) void prep_x_kernel(const float* __restrict__ x,
                                                     __hip_bfloat16* __restrict__ xn) {
  __shared__ float tile[128][97];
  int h = blockIdx.x;   // 0..95
  int b = blockIdx.y;   // 0..31
  const float* src = x + (size_t)b * 128 * 9216 + h * 96;
  for (int f = threadIdx.x; f < 3072; f += 512) {   // 128 ic x 24 float4
    int ic = f / 24, w4 = f - ic * 24;
    float4 v = *(const float4*)(src + (size_t)ic * 9216 + w4 * 4);
    tile[ic][w4 * 4 + 0] = v.x; tile[ic][w4 * 4 + 1] = v.y;
    tile[ic][w4 * 4 + 2] = v.z; tile[ic][w4 * 4 + 3] = v.w;
  }
  __syncthreads();
  __hip_bfloat16* bb  = xn + (size_t)b * 4 * 307328;
  __hip_bfloat16* dst = bb + (h + 1) * 3136 + 32;
  for (int o = threadIdx.x; o < 1536; o += 512) {   // 16B units
    int grp = o / 384, rem = o - grp * 384;
    int w = rem >> 2, chunk = rem & 3;
    __hip_bfloat16 tmp[8];
    #pragma unroll
    for (int e = 0; e < 8; e++) tmp[e] = __float2bfloat16(tile[grp * 32 + chunk * 8 + e][w]);
    *(uint4*)(dst + (size_t)grp * 307328 + w * 32 + chunk * 8) = *(uint4*)tmp;
  }
  // left/right halo cells of this row (ph = h+1)
  if (threadIdx.x < 32) {
    int u = threadIdx.x;
    int grp = u >> 3, rem = u & 7;
    int pw = (rem >> 2) ? 97 : 0, k = rem & 3;
    *(uint4*)(bb + (size_t)grp * 307328 + ((h + 1) * 98 + pw) * 32 + k * 8) = make_uint4(0, 0, 0, 0);
  }
  // top/bottom halo rows
  if (h == 0 || h == 95) {
    int ph = (h == 0) ? 0 : 97;
    for (int u = threadIdx.x; u < 1568; u += 512) {
      int grp = u / 392, rem = u - grp * 392;
      int pw = rem >> 2, k = rem & 3;
      *(uint4*)(bb + (size_t)grp * 307328 + (ph * 98 + pw) * 32 + k * 8) = make_uint4(0, 0, 0, 0);
    }
  }
}

// ---------- prep_w fused: z projections + merge -> Wt[b][grp4][tap9][oc128][32ic] bf16 ----------
__global__ __launch_bounds__(256) void prep_w_kernel(
    const float* __restrict__ z, const float* __restrict__ gw,
    const float* __restrict__ pww, const float* __restrict__ dww,
    const float* __restrict__ base, __hip_bfloat16* __restrict__ Wt) {
  __shared__ float zs[2048];
  __shared__ float res[138][33];   // row 0=gate, 1..9=dw taps, 10..137=pw ic
  int oc = blockIdx.x;             // 0..127
  for (int i = threadIdx.x; i < 2048; i += 256) zs[i] = z[i];
  __syncthreads();
  int row = threadIdx.x;
  if (row < 138) {
    const float* wrow = (row == 0) ? gw + (size_t)oc * 64
                      : (row < 10) ? dww + ((size_t)oc * 9 + (row - 1)) * 64
                                   : pww + ((size_t)oc * 128 + (row - 10)) * 64;
    float wr[64];
    #pragma unroll
    for (int i = 0; i < 16; i++) {
      float4 v = ((const float4*)wrow)[i];
      wr[4*i] = v.x; wr[4*i+1] = v.y; wr[4*i+2] = v.z; wr[4*i+3] = v.w;
    }
    for (int b = 0; b < 32; b++) {
      float a = 0.f;
      #pragma unroll
      for (int i = 0; i < 64; i++) a += zs[b * 64 + i] * wr[i];
      res[row][b] = a;
    }
  }
  __syncthreads();
  for (int e = threadIdx.x; e < 18432; e += 256) {   // bf162 units
    int icp = e & 15;
    int r1 = e >> 4;
    int tap = r1 % 9, bg = r1 / 9;       // bg = b*4+grp
    int grp = bg & 3, b = bg >> 2;
    int ic = grp * 32 + icp * 2;
    float g = res[0][b], d = res[1 + tap][b];
    float p0 = res[10 + ic][b], p1 = res[11 + ic][b];
    const float* bp = base + ((size_t)(oc * 128 + ic)) * 9 + tap;
    __hip_bfloat162 o2 = {__float2bfloat16(bp[0] * g + p0 * d),
                          __float2bfloat16(bp[9] * g + p1 * d)};
    *(__hip_bfloat162*)(Wt + (((size_t)bg * 9 + tap) * 128 + oc) * 32 + icp * 2) = o2;
  }
}

// ---------- conv: 192px x 128oc per block, 96x64 waves, 32x32x16 MFMA, 36 phases ----------
__global__ __launch_bounds__(256, 3) void conv_kernel(
    const __hip_bfloat16* __restrict__ xn, const __hip_bfloat16* __restrict__ Wt,
    float* __restrict__ out) {
  __shared__ __align__(16) char smem[50176];
  char* const wqb = smem;              // 4 x 8192 B weight tap buffers
  char* const xt  = smem + 32768;      // 1088 slots x 16B = 17408 B ([8h][34w][32ic])

  int bid = blockIdx.x;
  int X = bid & 7, q = bid >> 3;       // XCD pin: 192 blocks (4 samples) per XCD
  int logical = X * 192 + q;
  int b   = logical / 48;
  int rem = logical - b * 48;
  int hr  = rem / 3;
  int wc  = rem - hr * 3;
  int h0 = hr * 6, w0 = wc * 32;

  int tid = threadIdx.x;
  int lane = tid & 63, wid = tid >> 6;
  int l31 = lane & 31, lh = lane >> 5;
  int wm = wid >> 1, wn = wid & 1;

  // A-row bases and B-frag LDS offsets
  int ar[3];
  #pragma unroll
  for (int i = 0; i < 3; i++) ar[i] = (wm * 3 + i) * 34 + l31;
  int boff[2][2];
  #pragma unroll
  for (int j = 0; j < 2; j++)
    #pragma unroll
    for (int kk = 0; kk < 2; kk++)
      boff[j][kk] = swz(wn * 64 + j * 32 + l31, kk * 2 + lh);

  // x-stage source offsets: 4 full wave-sweeps + shared 64-slot tail (all waves, same data)
  int xoff[5];
  #pragma unroll
  for (int j = 0; j < 5; j++) {
    int p = (j < 4) ? (j * 256 + tid) : (1024 + lane);
    int pair = p >> 3, v = (p & 7) ^ (pair & 7);
    int n = (pair << 1) | (v >> 2), k = v & 3;
    int hh = n / 34, ww = n - hh * 34;
    xoff[j] = ((h0 + hh) * 98 + (w0 + ww)) * 32 + k * 8;
  }
  // w-stage source offsets (2/thread per 8KB tap)
  int woff[2];
  #pragma unroll
  for (int i = 0; i < 2; i++) {
    int p = i * 256 + tid;
    int pair = p >> 3, v = (p & 7) ^ (pair & 7);
    int n = (pair << 1) | (v >> 2), k = v & 3;
    woff[i] = n * 32 + k * 8;
  }

  const __hip_bfloat16* xbase = xn + (size_t)b * 4 * 307328;
  const __hip_bfloat16* wbase = Wt + (size_t)b * 147456;

  f32x16 acc[3][2];
  #pragma unroll
  for (int i = 0; i < 3; i++)
    #pragma unroll
    for (int j = 0; j < 2; j++)
      #pragma unroll
      for (int e = 0; e < 16; e++) acc[i][j][e] = 0.f;

  // prologue: w(0), w(1), x(grp0)
  #pragma unroll
  for (int i = 0; i < 2; i++)
    load_lds16(wbase + woff[i], wqb + ((i * 256 + wid * 64) << 4));
  #pragma unroll
  for (int i = 0; i < 2; i++)
    load_lds16(wbase + 4096 + woff[i], wqb + 8192 + ((i * 256 + wid * 64) << 4));
  #pragma unroll
  for (int j = 0; j < 4; j++)
    load_lds16(xbase + xoff[j], xt + ((j * 256 + wid * 64) << 4));
  load_lds16(xbase + xoff[4], xt + (1024 << 4));

#define PH(S, VM, XBAR)                                                            \
  {                                                                                \
    constexpr int grp_ = (S) / 9, tap_ = (S) % 9;                                  \
    constexpr int dy_ = tap_ / 3, dx_ = tap_ % 3;                                  \
    if (XBAR) {                                                                    \
      __builtin_amdgcn_s_barrier();                                                \
      const __hip_bfloat16* xsrc = xbase + (size_t)grp_ * 307328;                  \
      _Pragma("unroll")                                                            \
      for (int j = 0; j < 4; j++)                                                  \
        load_lds16(xsrc + xoff[j], xt + ((j * 256 + wid * 64) << 4));              \
      load_lds16(xsrc + xoff[4], xt + (1024 << 4));                                \
    }                                                                              \
    if ((S) + 2 <= 35) {                                                           \
      const __hip_bfloat16* wsrc = wbase + (size_t)((S) + 2) * 4096;               \
      _Pragma("unroll")                                                            \
      for (int i = 0; i < 2; i++)                                                  \
        load_lds16(wsrc + woff[i],                                                 \
                   wqb + ((((S) + 2) & 3) << 13) + ((i * 256 + wid * 64) << 4));   \
    }                                                                              \
    asm volatile("s_waitcnt vmcnt(" #VM ")" ::: "memory");                         \
    __builtin_amdgcn_s_barrier();                                                  \
    const char* wc_ = wqb + (((S) & 3) << 13);                                     \
    bf16x8 bfr[2][2], afr[3][2];                                                   \
    _Pragma("unroll")                                                              \
    for (int j = 0; j < 2; j++)                                                    \
      _Pragma("unroll")                                                            \
      for (int kk = 0; kk < 2; kk++)                                               \
        bfr[j][kk] = *(const bf16x8*)(wc_ + boff[j][kk]);                          \
    _Pragma("unroll")                                                              \
    for (int i = 0; i < 3; i++) {                                                  \
      int n_ = ar[i] + (dy_ * 34 + dx_);                                           \
      _Pragma("unroll")                                                            \
      for (int kk = 0; kk < 2; kk++)                                               \
        afr[i][kk] = *(const bf16x8*)(xt + swz(n_, kk * 2 + lh));                  \
    }                                                                              \
    __builtin_amdgcn_s_setprio(1);                                                 \
    _Pragma("unroll")                                                              \
    for (int i = 0; i < 3; i++)                                                    \
      _Pragma("unroll")                                                            \
      for (int j = 0; j < 2; j++)                                                  \
        _Pragma("unroll")                                                          \
        for (int kk = 0; kk < 2; kk++)                                             \
          acc[i][j] = __builtin_amdgcn_mfma_f32_32x32x16_bf16(afr[i][kk],          \
                          bfr[j][kk], acc[i][j], 0, 0, 0);                         \
    __builtin_amdgcn_s_setprio(0);                                                 \
  }

  PH(0, 2, 0)  PH(1, 4, 0)  PH(2, 4, 0)  PH(3, 4, 0)  PH(4, 4, 0)  PH(5, 4, 0)
  PH(6, 4, 0)  PH(7, 4, 0)  PH(8, 4, 0)
  PH(9, 2, 1)  PH(10, 4, 0) PH(11, 4, 0) PH(12, 4, 0) PH(13, 4, 0) PH(14, 4, 0)
  PH(15, 4, 0) PH(16, 4, 0) PH(17, 4, 0)
  PH(18, 2, 1) PH(19, 4, 0) PH(20, 4, 0) PH(21, 4, 0) PH(22, 4, 0) PH(23, 4, 0)
  PH(24, 4, 0) PH(25, 4, 0) PH(26, 4, 0)
  PH(27, 2, 1) PH(28, 4, 0) PH(29, 4, 0) PH(30, 4, 0) PH(31, 4, 0) PH(32, 4, 0)
  PH(33, 4, 0) PH(34, 2, 0) PH(35, 0, 0)
#undef PH

  // epilogue: acc[i][j] covers h-row (h0+wm*3+i), oc = wn*64+j*32+l31, w = 8q+4*lh+r
  #pragma unroll
  for (int i = 0; i < 3; i++) {
    int h = h0 + wm * 3 + i;
    #pragma unroll
    for (int j = 0; j < 2; j++) {
      int oc = wn * 64 + j * 32 + l31;
      float* op = out + ((size_t)b * 128 + oc) * 9216 + h * 96 + w0 + 4 * lh;
      #pragma unroll
      for (int qq = 0; qq < 4; qq++) {
        f32x4 v = {acc[i][j][4 * qq + 0], acc[i][j][4 * qq + 1],
                   acc[i][j][4 * qq + 2], acc[i][j][4 * qq + 3]};
        *(f32x4*)(op + 8 * qq) = v;
      }
    }
  }
}

extern "C" void kernel_launch(void* const* d_in, const int* in_sizes, int n_in,
                              void* d_out, int out_size, void* d_ws, size_t ws_size,
                              hipStream_t stream) {
  const float* x   = (const float*)d_in[0];
  const float* z   = (const float*)d_in[1];
  const float* bw  = (const float*)d_in[2];
  const float* gw  = (const float*)d_in[3];
  const float* pww = (const float*)d_in[4];
  const float* dww = (const float*)d_in[5];
  float* out = (float*)d_out;

  char* ws = (char*)d_ws;
  __hip_bfloat16* xn = (__hip_bfloat16*)ws;                       // 78,675,968 B (padded)
  __hip_bfloat16* Wt = (__hip_bfloat16*)(ws + 78675968);          //  9,437,184 B

  hipLaunchKernelGGL(prep_x_kernel, dim3(96, 32), dim3(512), 0, stream, x, xn);
  hipLaunchKernelGGL(prep_w_kernel, dim3(128), dim3(256), 0, stream,
                     z, gw, pww, dww, bw, Wt);
  hipLaunchKernelGGL(conv_kernel,   dim3(1536), dim3(256), 0, stream, xn, Wt, out);
}

// Round 7
// 180.114 us; speedup vs baseline: 1.1341x; 1.1341x over previous
//
#include <hip/hip_runtime.h>
#include <hip/hip_bf16.h>

typedef __bf16 bf16x8 __attribute__((ext_vector_type(8)));
typedef float f32x4 __attribute__((ext_vector_type(4)));
typedef float f32x16 __attribute__((ext_vector_type(16)));

// row-pair XOR swizzle: logical (row n of 64B, 16B-chunk k) -> byte offset
__device__ __forceinline__ int swz(int n, int k) {
  int pair = n >> 1;
  int s = (((n & 1) << 2) | k) ^ (pair & 7);
  return (pair << 7) + (s << 4);
}

__device__ __forceinline__ void load_lds16(const void* g, void* l) {
  __builtin_amdgcn_global_load_lds((const __attribute__((address_space(1))) void*)g,
                                   (__attribute__((address_space(3))) void*)l, 16, 0, 0);
}

// ---------- prep_x: f32 NCHW -> bf16 padded [b][grp4][98][98][32ic], border-zero fused ----------
__global__ __launch_bounds__(512) void prep_x_kernel(const float* __restrict__ x,
                                                     __hip_bfloat16* __restrict__ xn) {
  __shared__ float tile[128][97];
  int h = blockIdx.x;   // 0..95
  int b = blockIdx.y;   // 0..31
  const float* src = x + (size_t)b * 128 * 9216 + h * 96;
  for (int f = threadIdx.x; f < 3072; f += 512) {   // 128 ic x 24 float4
    int ic = f / 24, w4 = f - ic * 24;
    float4 v = *(const float4*)(src + (size_t)ic * 9216 + w4 * 4);
    tile[ic][w4 * 4 + 0] = v.x; tile[ic][w4 * 4 + 1] = v.y;
    tile[ic][w4 * 4 + 2] = v.z; tile[ic][w4 * 4 + 3] = v.w;
  }
  __syncthreads();
  __hip_bfloat16* bb  = xn + (size_t)b * 4 * 307328;
  __hip_bfloat16* dst = bb + (h + 1) * 3136 + 32;
  for (int o = threadIdx.x; o < 1536; o += 512) {   // 16B units
    int grp = o / 384, rem = o - grp * 384;
    int w = rem >> 2, chunk = rem & 3;
    __hip_bfloat16 tmp[8];
    #pragma unroll
    for (int e = 0; e < 8; e++) tmp[e] = __float2bfloat16(tile[grp * 32 + chunk * 8 + e][w]);
    *(uint4*)(dst + (size_t)grp * 307328 + w * 32 + chunk * 8) = *(uint4*)tmp;
  }
  // left/right halo cells of this row (ph = h+1)
  if (threadIdx.x < 32) {
    int u = threadIdx.x;
    int grp = u >> 3, rem = u & 7;
    int pw = (rem >> 2) ? 97 : 0, k = rem & 3;
    *(uint4*)(bb + (size_t)grp * 307328 + ((h + 1) * 98 + pw) * 32 + k * 8) = make_uint4(0, 0, 0, 0);
  }
  // top/bottom halo rows
  if (h == 0 || h == 95) {
    int ph = (h == 0) ? 0 : 97;
    for (int u = threadIdx.x; u < 1568; u += 512) {
      int grp = u / 392, rem = u - grp * 392;
      int pw = rem >> 2, k = rem & 3;
      *(uint4*)(bb + (size_t)grp * 307328 + (ph * 98 + pw) * 32 + k * 8) = make_uint4(0, 0, 0, 0);
    }
  }
}

// ---------- prep_w fused: z projections + merge -> Wt[b][grp4][tap9][oc128][32ic] bf16 ----------
__global__ __launch_bounds__(256) void prep_w_kernel(
    const float* __restrict__ z, const float* __restrict__ gw,
    const float* __restrict__ pww, const float* __restrict__ dww,
    const float* __restrict__ base, __hip_bfloat16* __restrict__ Wt) {
  __shared__ float zs[2048];
  __shared__ float res[138][33];   // row 0=gate, 1..9=dw taps, 10..137=pw ic
  int oc = blockIdx.x;             // 0..127
  for (int i = threadIdx.x; i < 2048; i += 256) zs[i] = z[i];
  __syncthreads();
  int row = threadIdx.x;
  if (row < 138) {
    const float* wrow = (row == 0) ? gw + (size_t)oc * 64
                      : (row < 10) ? dww + ((size_t)oc * 9 + (row - 1)) * 64
                                   : pww + ((size_t)oc * 128 + (row - 10)) * 64;
    float wr[64];
    #pragma unroll
    for (int i = 0; i < 16; i++) {
      float4 v = ((const float4*)wrow)[i];
      wr[4*i] = v.x; wr[4*i+1] = v.y; wr[4*i+2] = v.z; wr[4*i+3] = v.w;
    }
    for (int b = 0; b < 32; b++) {
      float a = 0.f;
      #pragma unroll
      for (int i = 0; i < 64; i++) a += zs[b * 64 + i] * wr[i];
      res[row][b] = a;
    }
  }
  __syncthreads();
  for (int e = threadIdx.x; e < 18432; e += 256) {   // bf162 units
    int icp = e & 15;
    int r1 = e >> 4;
    int tap = r1 % 9, bg = r1 / 9;       // bg = b*4+grp
    int grp = bg & 3, b = bg >> 2;
    int ic = grp * 32 + icp * 2;
    float g = res[0][b], d = res[1 + tap][b];
    float p0 = res[10 + ic][b], p1 = res[11 + ic][b];
    const float* bp = base + ((size_t)(oc * 128 + ic)) * 9 + tap;
    __hip_bfloat162 o2 = {__float2bfloat16(bp[0] * g + p0 * d),
                          __float2bfloat16(bp[9] * g + p1 * d)};
    *(__hip_bfloat162*)(Wt + (((size_t)bg * 9 + tap) * 128 + oc) * 32 + icp * 2) = o2;
  }
}

// ---------- conv: 192px x 128oc per block, 96x64 waves, 32x32x16 MFMA, 12 dy-phases ----------
__global__ __launch_bounds__(256, 2) void conv_kernel(
    const __hip_bfloat16* __restrict__ xn, const __hip_bfloat16* __restrict__ Wt,
    float* __restrict__ out) {
  __shared__ __align__(16) char smem[66560];
  char* const wqb = smem;              // 2 x 24576 B (dy-block: 3 taps x 128 oc x 32 ic)
  char* const xt  = smem + 49152;      // 1088 slots x 16B = 17408 B ([8h][34w][32ic])

  int bid = blockIdx.x;
  int X = bid & 7, q = bid >> 3;       // XCD pin: 192 blocks (4 samples) per XCD
  int logical = X * 192 + q;
  int b   = logical / 48;
  int rem = logical - b * 48;
  int hr  = rem / 3;
  int wc  = rem - hr * 3;
  int h0 = hr * 6, w0 = wc * 32;

  int tid = threadIdx.x;
  int lane = tid & 63, wid = tid >> 6;
  int l31 = lane & 31, lh = lane >> 5;
  int wm = wid >> 1, wn = wid & 1;

  // A-frag offsets: rr = i+dy in [0,5) -> 30 precomputed entries
  int aoff[5][3][2];
  #pragma unroll
  for (int rr = 0; rr < 5; rr++)
    #pragma unroll
    for (int dx = 0; dx < 3; dx++)
      #pragma unroll
      for (int kk = 0; kk < 2; kk++)
        aoff[rr][dx][kk] = swz((wm * 3 + rr) * 34 + l31 + dx, kk * 2 + lh);
  // B-frag offsets (dx handled as +8192B immediate: +128 rows keeps pair&7)
  int boff[2][2];
  #pragma unroll
  for (int j = 0; j < 2; j++)
    #pragma unroll
    for (int kk = 0; kk < 2; kk++)
      boff[j][kk] = swz(wn * 64 + j * 32 + l31, kk * 2 + lh);

  // x-stage source offsets: 4 full wave-sweeps + shared 64-slot tail
  int xoff[5];
  #pragma unroll
  for (int j = 0; j < 5; j++) {
    int p = (j < 4) ? (j * 256 + tid) : (1024 + lane);
    int pair = p >> 3, v = (p & 7) ^ (pair & 7);
    int n = (pair << 1) | (v >> 2), k = v & 3;
    int hh = n / 34, ww = n - hh * 34;
    xoff[j] = ((h0 + hh) * 98 + (w0 + ww)) * 32 + k * 8;
  }
  // w-stage source offsets: 6/thread per 24KB dy-block
  int wsoff[6];
  #pragma unroll
  for (int i = 0; i < 6; i++) {
    int p = i * 256 + tid;
    int pair = p >> 3, v = (p & 7) ^ (pair & 7);
    int n = (pair << 1) | (v >> 2), k = v & 3;
    wsoff[i] = n * 32 + k * 8;
  }

  const __hip_bfloat16* xbase = xn + (size_t)b * 4 * 307328;
  const __hip_bfloat16* wbase = Wt + (size_t)b * 147456;

  f32x16 acc[3][2];
  #pragma unroll
  for (int i = 0; i < 3; i++)
    #pragma unroll
    for (int j = 0; j < 2; j++)
      #pragma unroll
      for (int e = 0; e < 16; e++) acc[i][j][e] = 0.f;

  // prologue: w(phase0) -> wqb0, x(grp0) -> xt
  #pragma unroll
  for (int i = 0; i < 6; i++)
    load_lds16(wbase + wsoff[i], wqb + ((i * 256 + wid * 64) << 4));
  #pragma unroll
  for (int j = 0; j < 4; j++)
    load_lds16(xbase + xoff[j], xt + ((j * 256 + wid * 64) << 4));
  load_lds16(xbase + xoff[4], xt + (1024 << 4));

#define PH(S, DOX, VM)                                                             \
  {                                                                                \
    constexpr int grp_ = (S) / 3, dy_ = (S) % 3;                                   \
    __builtin_amdgcn_s_barrier();                                                  \
    if (DOX) {                                                                     \
      const __hip_bfloat16* xsrc = xbase + (size_t)grp_ * 307328;                  \
      _Pragma("unroll")                                                            \
      for (int j = 0; j < 4; j++)                                                  \
        load_lds16(xsrc + xoff[j], xt + ((j * 256 + wid * 64) << 4));              \
      load_lds16(xsrc + xoff[4], xt + (1024 << 4));                                \
    }                                                                              \
    if ((S) < 11) {                                                                \
      constexpr int sn_ = (S) + 1, g2_ = sn_ / 3, d2_ = sn_ % 3;                   \
      const __hip_bfloat16* wsrc = wbase + (size_t)(g2_ * 9 + d2_ * 3) * 4096;     \
      _Pragma("unroll")                                                            \
      for (int i = 0; i < 6; i++)                                                  \
        load_lds16(wsrc + wsoff[i],                                                \
                   wqb + ((sn_ & 1) * 24576) + ((i * 256 + wid * 64) << 4));       \
    }                                                                              \
    asm volatile("s_waitcnt vmcnt(" #VM ")" ::: "memory");                         \
    __builtin_amdgcn_s_barrier();                                                  \
    __builtin_amdgcn_s_setprio(1);                                                 \
    const char* wc_ = wqb + (((S) & 1) * 24576);                                   \
    _Pragma("unroll")                                                              \
    for (int dx = 0; dx < 3; dx++) {                                               \
      bf16x8 bfr[2][2], afr[3][2];                                                 \
      _Pragma("unroll")                                                            \
      for (int j = 0; j < 2; j++)                                                  \
        _Pragma("unroll")                                                          \
        for (int kk = 0; kk < 2; kk++)                                             \
          bfr[j][kk] = *(const bf16x8*)(wc_ + boff[j][kk] + dx * 8192);            \
      _Pragma("unroll")                                                            \
      for (int i = 0; i < 3; i++)                                                  \
        _Pragma("unroll")                                                          \
        for (int kk = 0; kk < 2; kk++)                                             \
          afr[i][kk] = *(const bf16x8*)(xt + aoff[i + dy_][dx][kk]);               \
      _Pragma("unroll")                                                            \
      for (int i = 0; i < 3; i++)                                                  \
        _Pragma("unroll")                                                          \
        for (int j = 0; j < 2; j++)                                                \
          _Pragma("unroll")                                                        \
          for (int kk = 0; kk < 2; kk++)                                           \
            acc[i][j] = __builtin_amdgcn_mfma_f32_32x32x16_bf16(afr[i][kk],        \
                            bfr[j][kk], acc[i][j], 0, 0, 0);                       \
    }                                                                              \
    __builtin_amdgcn_s_setprio(0);                                                 \
  }

  PH(0, 0, 6)  PH(1, 0, 6)  PH(2, 0, 6)
  PH(3, 1, 6)  PH(4, 0, 6)  PH(5, 0, 6)
  PH(6, 1, 6)  PH(7, 0, 6)  PH(8, 0, 6)
  PH(9, 1, 6)  PH(10, 0, 6) PH(11, 0, 0)
#undef PH

  // epilogue: acc[i][j] covers h-row (h0+wm*3+i), oc = wn*64+j*32+l31
  #pragma unroll
  for (int i = 0; i < 3; i++) {
    int h = h0 + wm * 3 + i;
    #pragma unroll
    for (int j = 0; j < 2; j++) {
      int oc = wn * 64 + j * 32 + l31;
      float* op = out + ((size_t)b * 128 + oc) * 9216 + h * 96 + w0 + 4 * lh;
      #pragma unroll
      for (int qq = 0; qq < 4; qq++) {
        f32x4 v = {acc[i][j][4 * qq + 0], acc[i][j][4 * qq + 1],
                   acc[i][j][4 * qq + 2], acc[i][j][4 * qq + 3]};
        *(f32x4*)(op + 8 * qq) = v;
      }
    }
  }
}

extern "C" void kernel_launch(void* const* d_in, const int* in_sizes, int n_in,
                              void* d_out, int out_size, void* d_ws, size_t ws_size,
                              hipStream_t stream) {
  const float* x   = (const float*)d_in[0];
  const float* z   = (const float*)d_in[1];
  const float* bw  = (const float*)d_in[2];
  const float* gw  = (const float*)d_in[3];
  const float* pww = (const float*)d_in[4];
  const float* dww = (const float*)d_in[5];
  float* out = (float*)d_out;

  char* ws = (char*)d_ws;
  __hip_bfloat16* xn = (__hip_bfloat16*)ws;                       // 78,675,968 B (padded)
  __hip_bfloat16* Wt = (__hip_bfloat16*)(ws + 78675968);          //  9,437,184 B

  hipLaunchKernelGGL(prep_x_kernel, dim3(96, 32), dim3(512), 0, stream, x, xn);
  hipLaunchKernelGGL(prep_w_kernel, dim3(128), dim3(256), 0, stream,
                     z, gw, pww, dww, bw, Wt);
  hipLaunchKernelGGL(conv_kernel,   dim3(1536), dim3(256), 0, stream, xn, Wt, out);
}

// Round 8
// 174.819 us; speedup vs baseline: 1.1685x; 1.0303x over previous
//
#include <hip/hip_runtime.h>
#include <hip/hip_bf16.h>

typedef __bf16 bf16x8 __attribute__((ext_vector_type(8)));
typedef float f32x4 __attribute__((ext_vector_type(4)));
typedef float f32x16 __attribute__((ext_vector_type(16)));

// row-pair XOR swizzle: logical (row n of 64B, 16B-chunk k) -> byte offset
__device__ __forceinline__ int swz(int n, int k) {
  int pair = n >> 1;
  int s = (((n & 1) << 2) | k) ^ (pair & 7);
  return (pair << 7) + (s << 4);
}

__device__ __forceinline__ void load_lds16(const void* g, void* l) {
  __builtin_amdgcn_global_load_lds((const __attribute__((address_space(1))) void*)g,
                                   (__attribute__((address_space(3))) void*)l, 16, 0, 0);
}

// ---------- prep_x: f32 NCHW -> bf16 padded [b][grp4][98][98][32ic], border-zero fused ----------
__global__ __launch_bounds__(512) void prep_x_kernel(const float* __restrict__ x,
                                                     __hip_bfloat16* __restrict__ xn) {
  __shared__ float tile[128][97];
  int h = blockIdx.x;   // 0..95
  int b = blockIdx.y;   // 0..31
  const float* src = x + (size_t)b * 128 * 9216 + h * 96;
  for (int f = threadIdx.x; f < 3072; f += 512) {   // 128 ic x 24 float4
    int ic = f / 24, w4 = f - ic * 24;
    float4 v = *(const float4*)(src + (size_t)ic * 9216 + w4 * 4);
    tile[ic][w4 * 4 + 0] = v.x; tile[ic][w4 * 4 + 1] = v.y;
    tile[ic][w4 * 4 + 2] = v.z; tile[ic][w4 * 4 + 3] = v.w;
  }
  __syncthreads();
  __hip_bfloat16* bb  = xn + (size_t)b * 4 * 307328;
  __hip_bfloat16* dst = bb + (h + 1) * 3136 + 32;
  for (int o = threadIdx.x; o < 1536; o += 512) {   // 16B units
    int grp = o / 384, rem = o - grp * 384;
    int w = rem >> 2, chunk = rem & 3;
    __hip_bfloat16 tmp[8];
    #pragma unroll
    for (int e = 0; e < 8; e++) tmp[e] = __float2bfloat16(tile[grp * 32 + chunk * 8 + e][w]);
    *(uint4*)(dst + (size_t)grp * 307328 + w * 32 + chunk * 8) = *(uint4*)tmp;
  }
  // left/right halo cells of this row (ph = h+1)
  if (threadIdx.x < 32) {
    int u = threadIdx.x;
    int grp = u >> 3, rem = u & 7;
    int pw = (rem >> 2) ? 97 : 0, k = rem & 3;
    *(uint4*)(bb + (size_t)grp * 307328 + ((h + 1) * 98 + pw) * 32 + k * 8) = make_uint4(0, 0, 0, 0);
  }
  // top/bottom halo rows
  if (h == 0 || h == 95) {
    int ph = (h == 0) ? 0 : 97;
    for (int u = threadIdx.x; u < 1568; u += 512) {
      int grp = u / 392, rem = u - grp * 392;
      int pw = rem >> 2, k = rem & 3;
      *(uint4*)(bb + (size_t)grp * 307328 + (ph * 98 + pw) * 32 + k * 8) = make_uint4(0, 0, 0, 0);
    }
  }
}

// ---------- prep_w fused: z projections + merge -> Wt[b][grp4][dx3][dy3][oc128][32ic] ----------
__global__ __launch_bounds__(256) void prep_w_kernel(
    const float* __restrict__ z, const float* __restrict__ gw,
    const float* __restrict__ pww, const float* __restrict__ dww,
    const float* __restrict__ base, __hip_bfloat16* __restrict__ Wt) {
  __shared__ float zs[2048];
  __shared__ float res[138][33];   // row 0=gate, 1..9=dw taps, 10..137=pw ic
  int oc = blockIdx.x;             // 0..127
  for (int i = threadIdx.x; i < 2048; i += 256) zs[i] = z[i];
  __syncthreads();
  int row = threadIdx.x;
  if (row < 138) {
    const float* wrow = (row == 0) ? gw + (size_t)oc * 64
                      : (row < 10) ? dww + ((size_t)oc * 9 + (row - 1)) * 64
                                   : pww + ((size_t)oc * 128 + (row - 10)) * 64;
    float wr[64];
    #pragma unroll
    for (int i = 0; i < 16; i++) {
      float4 v = ((const float4*)wrow)[i];
      wr[4*i] = v.x; wr[4*i+1] = v.y; wr[4*i+2] = v.z; wr[4*i+3] = v.w;
    }
    for (int b = 0; b < 32; b++) {
      float a = 0.f;
      #pragma unroll
      for (int i = 0; i < 64; i++) a += zs[b * 64 + i] * wr[i];
      res[row][b] = a;
    }
  }
  __syncthreads();
  for (int e = threadIdx.x; e < 18432; e += 256) {   // bf162 units
    int icp = e & 15;
    int r1 = e >> 4;
    int tap = r1 % 9, bg = r1 / 9;       // bg = b*4+grp
    int grp = bg & 3, b = bg >> 2;
    int ic = grp * 32 + icp * 2;
    int dy = tap / 3, dx = tap - dy * 3;
    float g = res[0][b], d = res[1 + tap][b];
    float p0 = res[10 + ic][b], p1 = res[11 + ic][b];
    const float* bp = base + ((size_t)(oc * 128 + ic)) * 9 + tap;
    __hip_bfloat162 o2 = {__float2bfloat16(bp[0] * g + p0 * d),
                          __float2bfloat16(bp[9] * g + p1 * d)};
    // slot = dx*3 + dy  (dx-major for dx-outer conv phases)
    *(__hip_bfloat162*)(Wt + (((size_t)bg * 9 + dx * 3 + dy) * 128 + oc) * 32 + icp * 2) = o2;
  }
}

// ---------- conv: 192px x 128oc per block, 96x64 waves, 32x32x16 MFMA, 12 dx-phases ----------
__global__ __launch_bounds__(256, 2) void conv_kernel(
    const __hip_bfloat16* __restrict__ xn, const __hip_bfloat16* __restrict__ Wt,
    float* __restrict__ out) {
  __shared__ __align__(16) char smem[66560];
  char* const wqb = smem;              // 2 x 24576 B (dx-block: 3 dy x 128 oc x 32 ic)
  char* const xt  = smem + 49152;      // 1088 slots x 16B = 17408 B ([8h][34w][32ic])

  int bid = blockIdx.x;
  int X = bid & 7, q = bid >> 3;       // XCD pin: 192 blocks (4 samples) per XCD
  int logical = X * 192 + q;
  int b   = logical / 48;
  int rem = logical - b * 48;
  int hr  = rem / 3;
  int wc  = rem - hr * 3;
  int h0 = hr * 6, w0 = wc * 32;

  int tid = threadIdx.x;
  int lane = tid & 63, wid = tid >> 6;
  int l31 = lane & 31, lh = lane >> 5;
  int wm = wid >> 1, wn = wid & 1;

  // A-frag offsets: rr = i+dy in [0,5), dx = phase shift -> 30 precomputed entries
  int aoff[5][3][2];
  #pragma unroll
  for (int rr = 0; rr < 5; rr++)
    #pragma unroll
    for (int dx = 0; dx < 3; dx++)
      #pragma unroll
      for (int kk = 0; kk < 2; kk++)
        aoff[rr][dx][kk] = swz((wm * 3 + rr) * 34 + l31 + dx, kk * 2 + lh);
  // B-frag offsets (dy handled as +8192B immediate: +128 rows keeps pair&7)
  int boff[2][2];
  #pragma unroll
  for (int j = 0; j < 2; j++)
    #pragma unroll
    for (int kk = 0; kk < 2; kk++)
      boff[j][kk] = swz(wn * 64 + j * 32 + l31, kk * 2 + lh);

  // x-stage source offsets: 4 full wave-sweeps + shared 64-slot tail
  int xoff[5];
  #pragma unroll
  for (int j = 0; j < 5; j++) {
    int p = (j < 4) ? (j * 256 + tid) : (1024 + lane);
    int pair = p >> 3, v = (p & 7) ^ (pair & 7);
    int n = (pair << 1) | (v >> 2), k = v & 3;
    int hh = n / 34, ww = n - hh * 34;
    xoff[j] = ((h0 + hh) * 98 + (w0 + ww)) * 32 + k * 8;
  }
  // w-stage source offsets: 6/thread per 24KB dx-block
  int wsoff[6];
  #pragma unroll
  for (int i = 0; i < 6; i++) {
    int p = i * 256 + tid;
    int pair = p >> 3, v = (p & 7) ^ (pair & 7);
    int n = (pair << 1) | (v >> 2), k = v & 3;
    wsoff[i] = n * 32 + k * 8;
  }

  const __hip_bfloat16* xbase = xn + (size_t)b * 4 * 307328;
  const __hip_bfloat16* wbase = Wt + (size_t)b * 147456;

  f32x16 acc[3][2];
  #pragma unroll
  for (int i = 0; i < 3; i++)
    #pragma unroll
    for (int j = 0; j < 2; j++)
      #pragma unroll
      for (int e = 0; e < 16; e++) acc[i][j][e] = 0.f;

  // prologue: w(phase0) -> wqb0, x(grp0) -> xt
  #pragma unroll
  for (int i = 0; i < 6; i++)
    load_lds16(wbase + wsoff[i], wqb + ((i * 256 + wid * 64) << 4));
  #pragma unroll
  for (int j = 0; j < 4; j++)
    load_lds16(xbase + xoff[j], xt + ((j * 256 + wid * 64) << 4));
  load_lds16(xbase + xoff[4], xt + (1024 << 4));

#define PH(S, DOX, VM)                                                             \
  {                                                                                \
    constexpr int grp_ = (S) / 3, dx_ = (S) % 3;                                   \
    __builtin_amdgcn_s_barrier();                                                  \
    if (DOX) {                                                                     \
      const __hip_bfloat16* xsrc = xbase + (size_t)grp_ * 307328;                  \
      _Pragma("unroll")                                                            \
      for (int j = 0; j < 4; j++)                                                  \
        load_lds16(xsrc + xoff[j], xt + ((j * 256 + wid * 64) << 4));              \
      load_lds16(xsrc + xoff[4], xt + (1024 << 4));                                \
    }                                                                              \
    if ((S) < 11) {                                                                \
      const __hip_bfloat16* wsrc = wbase + (size_t)((S) + 1) * 12288;              \
      _Pragma("unroll")                                                            \
      for (int i = 0; i < 6; i++)                                                  \
        load_lds16(wsrc + wsoff[i],                                                \
                   wqb + ((((S) + 1) & 1) * 24576) + ((i * 256 + wid * 64) << 4)); \
    }                                                                              \
    asm volatile("s_waitcnt vmcnt(" #VM ")" ::: "memory");                         \
    __builtin_amdgcn_s_barrier();                                                  \
    const char* wc_ = wqb + (((S) & 1) * 24576);                                   \
    bf16x8 afr[5][2];                                                              \
    _Pragma("unroll")                                                              \
    for (int rr = 0; rr < 5; rr++)                                                 \
      _Pragma("unroll")                                                            \
      for (int kk = 0; kk < 2; kk++)                                               \
        afr[rr][kk] = *(const bf16x8*)(xt + aoff[rr][dx_][kk]);                    \
    _Pragma("unroll")                                                              \
    for (int dy = 0; dy < 3; dy++) {                                               \
      bf16x8 bfr[2][2];                                                            \
      _Pragma("unroll")                                                            \
      for (int j = 0; j < 2; j++)                                                  \
        _Pragma("unroll")                                                          \
        for (int kk = 0; kk < 2; kk++)                                             \
          bfr[j][kk] = *(const bf16x8*)(wc_ + boff[j][kk] + dy * 8192);            \
      __builtin_amdgcn_s_setprio(1);                                               \
      _Pragma("unroll")                                                            \
      for (int i = 0; i < 3; i++)                                                  \
        _Pragma("unroll")                                                          \
        for (int j = 0; j < 2; j++)                                                \
          _Pragma("unroll")                                                        \
          for (int kk = 0; kk < 2; kk++)                                           \
            acc[i][j] = __builtin_amdgcn_mfma_f32_32x32x16_bf16(afr[i + dy][kk],   \
                            bfr[j][kk], acc[i][j], 0, 0, 0);                       \
      __builtin_amdgcn_s_setprio(0);                                               \
    }                                                                              \
  }

  PH(0, 0, 6)  PH(1, 0, 6)  PH(2, 0, 6)
  PH(3, 1, 6)  PH(4, 0, 6)  PH(5, 0, 6)
  PH(6, 1, 6)  PH(7, 0, 6)  PH(8, 0, 6)
  PH(9, 1, 6)  PH(10, 0, 6) PH(11, 0, 0)
#undef PH

  // epilogue: acc[i][j] covers h-row (h0+wm*3+i), oc = wn*64+j*32+l31
  #pragma unroll
  for (int i = 0; i < 3; i++) {
    int h = h0 + wm * 3 + i;
    #pragma unroll
    for (int j = 0; j < 2; j++) {
      int oc = wn * 64 + j * 32 + l31;
      float* op = out + ((size_t)b * 128 + oc) * 9216 + h * 96 + w0 + 4 * lh;
      #pragma unroll
      for (int qq = 0; qq < 4; qq++) {
        f32x4 v = {acc[i][j][4 * qq + 0], acc[i][j][4 * qq + 1],
                   acc[i][j][4 * qq + 2], acc[i][j][4 * qq + 3]};
        *(f32x4*)(op + 8 * qq) = v;
      }
    }
  }
}

extern "C" void kernel_launch(void* const* d_in, const int* in_sizes, int n_in,
                              void* d_out, int out_size, void* d_ws, size_t ws_size,
                              hipStream_t stream) {
  const float* x   = (const float*)d_in[0];
  const float* z   = (const float*)d_in[1];
  const float* bw  = (const float*)d_in[2];
  const float* gw  = (const float*)d_in[3];
  const float* pww = (const float*)d_in[4];
  const float* dww = (const float*)d_in[5];
  float* out = (float*)d_out;

  char* ws = (char*)d_ws;
  __hip_bfloat16* xn = (__hip_bfloat16*)ws;                       // 78,675,968 B (padded)
  __hip_bfloat16* Wt = (__hip_bfloat16*)(ws + 78675968);          //  9,437,184 B

  hipLaunchKernelGGL(prep_x_kernel, dim3(96, 32), dim3(512), 0, stream, x, xn);
  hipLaunchKernelGGL(prep_w_kernel, dim3(128), dim3(256), 0, stream,
                     z, gw, pww, dww, bw, Wt);
  hipLaunchKernelGGL(conv_kernel,   dim3(1536), dim3(256), 0, stream, xn, Wt, out);
}

// Round 9
// 173.805 us; speedup vs baseline: 1.1753x; 1.0058x over previous
//
#include <hip/hip_runtime.h>
#include <hip/hip_bf16.h>

typedef __bf16 bf16x8 __attribute__((ext_vector_type(8)));
typedef float f32x4 __attribute__((ext_vector_type(4)));
typedef float f32x16 __attribute__((ext_vector_type(16)));

__device__ __forceinline__ void load_lds16(const void* g, void* l) {
  __builtin_amdgcn_global_load_lds((const __attribute__((address_space(1))) void*)g,
                                   (__attribute__((address_space(3))) void*)l, 16, 0, 0);
}

// ---------- prep_x: f32 NCHW -> bf16 padded [b][grp4][98][98][32ic], border-zero fused ----------
__global__ __launch_bounds__(512) void prep_x_kernel(const float* __restrict__ x,
                                                     __hip_bfloat16* __restrict__ xn) {
  __shared__ float tile[128][97];
  int h = blockIdx.x;   // 0..95
  int b = blockIdx.y;   // 0..31
  const float* src = x + (size_t)b * 128 * 9216 + h * 96;
  for (int f = threadIdx.x; f < 3072; f += 512) {   // 128 ic x 24 float4
    int ic = f / 24, w4 = f - ic * 24;
    float4 v = *(const float4*)(src + (size_t)ic * 9216 + w4 * 4);
    tile[ic][w4 * 4 + 0] = v.x; tile[ic][w4 * 4 + 1] = v.y;
    tile[ic][w4 * 4 + 2] = v.z; tile[ic][w4 * 4 + 3] = v.w;
  }
  __syncthreads();
  __hip_bfloat16* bb  = xn + (size_t)b * 4 * 307328;
  __hip_bfloat16* dst = bb + (h + 1) * 3136 + 32;
  for (int o = threadIdx.x; o < 1536; o += 512) {   // 16B units
    int grp = o / 384, rem = o - grp * 384;
    int w = rem >> 2, chunk = rem & 3;
    __hip_bfloat16 tmp[8];
    #pragma unroll
    for (int e = 0; e < 8; e++) tmp[e] = __float2bfloat16(tile[grp * 32 + chunk * 8 + e][w]);
    *(uint4*)(dst + (size_t)grp * 307328 + w * 32 + chunk * 8) = *(uint4*)tmp;
  }
  // left/right halo cells of this row (ph = h+1)
  if (threadIdx.x < 32) {
    int u = threadIdx.x;
    int grp = u >> 3, rem = u & 7;
    int pw = (rem >> 2) ? 97 : 0, k = rem & 3;
    *(uint4*)(bb + (size_t)grp * 307328 + ((h + 1) * 98 + pw) * 32 + k * 8) = make_uint4(0, 0, 0, 0);
  }
  // top/bottom halo rows
  if (h == 0 || h == 95) {
    int ph = (h == 0) ? 0 : 97;
    for (int u = threadIdx.x; u < 1568; u += 512) {
      int grp = u / 392, rem = u - grp * 392;
      int pw = rem >> 2, k = rem & 3;
      *(uint4*)(bb + (size_t)grp * 307328 + (ph * 98 + pw) * 32 + k * 8) = make_uint4(0, 0, 0, 0);
    }
  }
}

// ---------- prep_w fused: z projections + merge -> Wt[b][grp4][dx3][dy3][oc128][32ic] ----------
__global__ __launch_bounds__(256) void prep_w_kernel(
    const float* __restrict__ z, const float* __restrict__ gw,
    const float* __restrict__ pww, const float* __restrict__ dww,
    const float* __restrict__ base, __hip_bfloat16* __restrict__ Wt) {
  __shared__ float zs[2048];
  __shared__ float res[138][33];   // row 0=gate, 1..9=dw taps, 10..137=pw ic
  int oc = blockIdx.x;             // 0..127
  for (int i = threadIdx.x; i < 2048; i += 256) zs[i] = z[i];
  __syncthreads();
  int row = threadIdx.x;
  if (row < 138) {
    const float* wrow = (row == 0) ? gw + (size_t)oc * 64
                      : (row < 10) ? dww + ((size_t)oc * 9 + (row - 1)) * 64
                                   : pww + ((size_t)oc * 128 + (row - 10)) * 64;
    float wr[64];
    #pragma unroll
    for (int i = 0; i < 16; i++) {
      float4 v = ((const float4*)wrow)[i];
      wr[4*i] = v.x; wr[4*i+1] = v.y; wr[4*i+2] = v.z; wr[4*i+3] = v.w;
    }
    for (int b = 0; b < 32; b++) {
      float a = 0.f;
      #pragma unroll
      for (int i = 0; i < 64; i++) a += zs[b * 64 + i] * wr[i];
      res[row][b] = a;
    }
  }
  __syncthreads();
  for (int e = threadIdx.x; e < 18432; e += 256) {   // bf162 units
    int icp = e & 15;
    int r1 = e >> 4;
    int tap = r1 % 9, bg = r1 / 9;       // bg = b*4+grp
    int grp = bg & 3, b = bg >> 2;
    int ic = grp * 32 + icp * 2;
    int dy = tap / 3, dx = tap - dy * 3;
    float g = res[0][b], d = res[1 + tap][b];
    float p0 = res[10 + ic][b], p1 = res[11 + ic][b];
    const float* bp = base + ((size_t)(oc * 128 + ic)) * 9 + tap;
    __hip_bfloat162 o2 = {__float2bfloat16(bp[0] * g + p0 * d),
                          __float2bfloat16(bp[9] * g + p1 * d)};
    // slot = dx*3 + dy  (dx-major for dx-outer conv phases)
    *(__hip_bfloat162*)(Wt + (((size_t)bg * 9 + dx * 3 + dy) * 128 + oc) * 32 + icp * 2) = o2;
  }
}

// ---------- conv: 192px x 128oc per block, 96x64 waves, 32x32x16 MFMA ----------
// Weights: global->VGPR reg-staged (rotating per-dy batches, lag-1 phase).
// x: LDS double-buffer, chunk-major [hh][k4][ww][16B] -> contiguous conflict-free A-reads.
// Barriers only at grp boundaries (4): vmcnt(0) + s_barrier.
__global__ __launch_bounds__(256, 2) void conv_kernel(
    const __hip_bfloat16* __restrict__ xn, const __hip_bfloat16* __restrict__ Wt,
    float* __restrict__ out) {
  __shared__ __align__(16) char smem[34816];   // 2 x 17408 B x-tiles

  int bid = blockIdx.x;
  int X = bid & 7, q = bid >> 3;       // XCD pin: 192 blocks (4 samples) per XCD
  int logical = X * 192 + q;
  int b   = logical / 48;
  int rem = logical - b * 48;
  int hr  = rem / 3;
  int wc  = rem - hr * 3;
  int h0 = hr * 6, w0 = wc * 32;

  int tid = threadIdx.x;
  int lane = tid & 63, wid = tid >> 6;
  int l31 = lane & 31, lh = lane >> 5;
  int wm = wid >> 1, wn = wid & 1;

  char* const xr0 = smem;
  char* const xr1 = smem + 17408;
  // per-lane A-read bases: + (i+dy)*2176 + kk*1088 + dx*16
  const char* xp0 = xr0 + wm * 3 * 2176 + l31 * 16 + lh * 544;
  const char* xp1 = xr1 + wm * 3 * 2176 + l31 * 16 + lh * 544;

  // x-stage source offsets (chunk-major slot t -> (hh, k, ww)); tail duplicated by all waves
  int xoff[5];
  #pragma unroll
  for (int j = 0; j < 5; j++) {
    int t = (j < 4) ? (j * 256 + tid) : (1024 + lane);
    int hh = t / 136, r2 = t - hh * 136;
    int k = r2 / 34, ww = r2 - k * 34;
    xoff[j] = ((h0 + hh) * 98 + (w0 + ww)) * 32 + k * 8;
  }

  const __hip_bfloat16* xbase = xn + (size_t)b * 4 * 307328;
  // per-lane weight base: lane reads oc = wn*64 + j*32 + l31, ic chunk (kk*2+lh)*8
  const __hip_bfloat16* wlb = Wt + (size_t)b * 147456 + (wn * 64 + l31) * 32 + lh * 8;

  f32x16 acc[3][2];
  #pragma unroll
  for (int i = 0; i < 3; i++)
    #pragma unroll
    for (int j = 0; j < 2; j++)
      #pragma unroll
      for (int e = 0; e < 16; e++) acc[i][j][e] = 0.f;

  bf16x8 wreg[3][2][2];

  // prologue: x(grp0) -> xr0; w(phase0: grp0,dx0, slots dy) -> regs
  #pragma unroll
  for (int j = 0; j < 4; j++)
    load_lds16(xbase + xoff[j], xr0 + ((j * 256 + wid * 64) << 4));
  load_lds16(xbase + xoff[4], xr0 + (1024 << 4));
  #pragma unroll
  for (int dy = 0; dy < 3; dy++)
    #pragma unroll
    for (int j = 0; j < 2; j++)
      #pragma unroll
      for (int kk = 0; kk < 2; kk++)
        wreg[dy][j][kk] = *(const bf16x8*)(wlb + dy * 4096 + j * 1024 + kk * 16);

#define PH(S)                                                                      \
  {                                                                                \
    constexpr int grp_ = (S) / 3, dx_ = (S) % 3;                                   \
    if constexpr ((S) % 3 == 0) {                                                  \
      asm volatile("s_waitcnt vmcnt(0)" ::: "memory");                             \
      __builtin_amdgcn_s_barrier();                                                \
    }                                                                              \
    const char* xw_ = ((grp_ & 1) ? xp1 : xp0);                                    \
    bf16x8 afr[5][2];                                                              \
    _Pragma("unroll")                                                              \
    for (int rr = 0; rr < 5; rr++)                                                 \
      _Pragma("unroll")                                                            \
      for (int kk = 0; kk < 2; kk++)                                               \
        afr[rr][kk] = *(const bf16x8*)(xw_ + rr * 2176 + kk * 1088 + dx_ * 16);    \
    if constexpr ((S) % 3 == 2 && (S) < 11) {                                      \
      char* xd_ = (((grp_ + 1) & 1) ? xr1 : xr0);                                  \
      const __hip_bfloat16* xsrc = xbase + (size_t)(grp_ + 1) * 307328;            \
      _Pragma("unroll")                                                            \
      for (int j = 0; j < 4; j++)                                                  \
        load_lds16(xsrc + xoff[j], xd_ + ((j * 256 + wid * 64) << 4));             \
      load_lds16(xsrc + xoff[4], xd_ + (1024 << 4));                               \
    }                                                                              \
    _Pragma("unroll")                                                              \
    for (int dy = 0; dy < 3; dy++) {                                               \
      __builtin_amdgcn_s_setprio(1);                                               \
      _Pragma("unroll")                                                            \
      for (int i = 0; i < 3; i++)                                                  \
        _Pragma("unroll")                                                          \
        for (int j = 0; j < 2; j++)                                                \
          _Pragma("unroll")                                                        \
          for (int kk = 0; kk < 2; kk++)                                           \
            acc[i][j] = __builtin_amdgcn_mfma_f32_32x32x16_bf16(afr[i + dy][kk],   \
                            wreg[dy][j][kk], acc[i][j], 0, 0, 0);                  \
      __builtin_amdgcn_s_setprio(0);                                               \
      if constexpr ((S) < 11) {                                                    \
        constexpr int sn_ = (S) + 1;                                               \
        constexpr int g2_ = sn_ / 3, dxn_ = sn_ % 3;                               \
        _Pragma("unroll")                                                          \
        for (int j = 0; j < 2; j++)                                                \
          _Pragma("unroll")                                                        \
          for (int kk = 0; kk < 2; kk++)                                           \
            wreg[dy][j][kk] = *(const bf16x8*)(wlb + g2_ * 36864 +                 \
                (dxn_ * 3 + dy) * 4096 + j * 1024 + kk * 16);                      \
      }                                                                            \
    }                                                                              \
  }

  PH(0)  PH(1)  PH(2)
  PH(3)  PH(4)  PH(5)
  PH(6)  PH(7)  PH(8)
  PH(9)  PH(10) PH(11)
#undef PH

  // epilogue: acc[i][j] covers h-row (h0+wm*3+i), oc = wn*64+j*32+l31
  #pragma unroll
  for (int i = 0; i < 3; i++) {
    int h = h0 + wm * 3 + i;
    #pragma unroll
    for (int j = 0; j < 2; j++) {
      int oc = wn * 64 + j * 32 + l31;
      float* op = out + ((size_t)b * 128 + oc) * 9216 + h * 96 + w0 + 4 * lh;
      #pragma unroll
      for (int qq = 0; qq < 4; qq++) {
        f32x4 v = {acc[i][j][4 * qq + 0], acc[i][j][4 * qq + 1],
                   acc[i][j][4 * qq + 2], acc[i][j][4 * qq + 3]};
        *(f32x4*)(op + 8 * qq) = v;
      }
    }
  }
}

extern "C" void kernel_launch(void* const* d_in, const int* in_sizes, int n_in,
                              void* d_out, int out_size, void* d_ws, size_t ws_size,
                              hipStream_t stream) {
  const float* x   = (const float*)d_in[0];
  const float* z   = (const float*)d_in[1];
  const float* bw  = (const float*)d_in[2];
  const float* gw  = (const float*)d_in[3];
  const float* pww = (const float*)d_in[4];
  const float* dww = (const float*)d_in[5];
  float* out = (float*)d_out;

  char* ws = (char*)d_ws;
  __hip_bfloat16* xn = (__hip_bfloat16*)ws;                       // 78,675,968 B (padded)
  __hip_bfloat16* Wt = (__hip_bfloat16*)(ws + 78675968);          //  9,437,184 B

  hipLaunchKernelGGL(prep_x_kernel, dim3(96, 32), dim3(512), 0, stream, x, xn);
  hipLaunchKernelGGL(prep_w_kernel, dim3(128), dim3(256), 0, stream,
                     z, gw, pww, dww, bw, Wt);
  hipLaunchKernelGGL(conv_kernel,   dim3(1536), dim3(256), 0, stream, xn, Wt, out);
}